// Round 1
// baseline (707.952 us; speedup 1.0000x reference)
//
#include <hip/hip_runtime.h>
#include <hip/hip_bf16.h>

#define DM   1024
#define DFF  4096
#define NH   16
#define HD   64
#define SEQ  2048
#define BATCH 4
#define NTOK (BATCH*SEQ)

typedef float  f32x4  __attribute__((ext_vector_type(4)));
typedef short  bf16x8 __attribute__((ext_vector_type(8)));

__device__ __forceinline__ unsigned short f2bf(float f) {
    unsigned int x = __builtin_bit_cast(unsigned int, f);
    x += 0x7fff + ((x >> 16) & 1);          // RNE; inputs finite
    return (unsigned short)(x >> 16);
}

__device__ __forceinline__ void gload_lds16(const void* g, void* l) {
    // dest is wave-uniform base; HW writes base + lane*16
    __builtin_amdgcn_global_load_lds(
        (const __attribute__((address_space(1))) unsigned int*)g,
        (__attribute__((address_space(3))) unsigned int*)l,
        16, 0, 0);
}

// ---------------- weight fp32 -> bf16 transpose:  W[K][N] -> Wt[N][K] ----------------
__global__ __launch_bounds__(256)
void convT_kernel(const float* __restrict__ W, unsigned short* __restrict__ Wt, int K, int N)
{
    __shared__ float tile[32][33];
    int n0 = blockIdx.x * 32, k0 = blockIdx.y * 32;
    int tx = threadIdx.x & 31, ty = threadIdx.x >> 5;   // 32 x 8
    #pragma unroll
    for (int i = 0; i < 4; ++i)
        tile[ty + i*8][tx] = W[(size_t)(k0 + ty + i*8) * N + n0 + tx];
    __syncthreads();
    #pragma unroll
    for (int i = 0; i < 4; ++i)
        Wt[(size_t)(n0 + ty + i*8) * K + k0 + tx] = f2bf(tile[tx][ty + i*8]);
}

// ---------------- RMSNorm: fp32 in -> bf16 out ----------------
__global__ __launch_bounds__(256)
void rmsnorm_kernel(const float* __restrict__ in, const float* __restrict__ w,
                    unsigned short* __restrict__ out)
{
    __shared__ float red[4];
    int row = blockIdx.x, t = threadIdx.x;
    float4 v = ((const float4*)(in + (size_t)row * DM))[t];
    float ss = v.x*v.x + v.y*v.y + v.z*v.z + v.w*v.w;
    #pragma unroll
    for (int m = 1; m < 64; m <<= 1) ss += __shfl_xor(ss, m);
    if ((t & 63) == 0) red[t >> 6] = ss;
    __syncthreads();
    float tot = red[0] + red[1] + red[2] + red[3];
    float rms = sqrtf(tot) * (1.f / 32.f);      // ||x|| / sqrt(1024)
    float inv = 1.f / (rms + 1e-8f);
    float4 wv = ((const float4*)w)[t];
    unsigned int lo = (unsigned int)f2bf(v.x*inv*wv.x) | ((unsigned int)f2bf(v.y*inv*wv.y) << 16);
    unsigned int hi = (unsigned int)f2bf(v.z*inv*wv.z) | ((unsigned int)f2bf(v.w*inv*wv.w) << 16);
    uint2 pk; pk.x = lo; pk.y = hi;
    *(uint2*)(out + (size_t)row * DM + t * 4) = pk;
}

// ---------------- GEMM: C = A(bf16 [M][K]) @ Bt^T(bf16 [N][K]) + bias, fused epilogues ----
// MODE 0: qkv scatter -> q,k (bf16 [B*H][S][64]), v transposed (bf16 [B*H][64][S])
// MODE 1: out = acc + bias + resid  (fp32)
// MODE 2: out = gelu(acc + bias)    (bf16)
// MODE 3: same as 1 (ff2 + residual -> d_out fp32)
template<int MODE>
__global__ __launch_bounds__(256)
void gemm_bf16(const unsigned short* __restrict__ A,
               const unsigned short* __restrict__ Bt,
               const float* __restrict__ bias,
               int M, int N, int K,
               const float* __restrict__ resid,
               float* __restrict__ outf,
               unsigned short* __restrict__ outb,
               unsigned short* __restrict__ q,
               unsigned short* __restrict__ kk,
               unsigned short* __restrict__ vt)
{
    __shared__ __align__(16) unsigned short As[128 * 64];
    __shared__ __align__(16) unsigned short Bs[128 * 64];
    const int tid = threadIdx.x;
    const int w = tid >> 6, l = tid & 63;
    const int lr = l & 15, lh = l >> 4;
    const int m0 = blockIdx.y * 128, n0 = blockIdx.x * 128;
    const int wr = (w >> 1) * 64, wc = (w & 1) * 64;

    f32x4 acc[4][4];
    #pragma unroll
    for (int i = 0; i < 4; ++i)
        #pragma unroll
        for (int j = 0; j < 4; ++j) acc[i][j] = {0.f, 0.f, 0.f, 0.f};

    const int nkt = K >> 6;
    for (int kt = 0; kt < nkt; ++kt) {
        __syncthreads();
        #pragma unroll
        for (int c = 0; c < 4; ++c) {
            int rbase = w * 32 + c * 8;
            int row = rbase + (l >> 3);
            int col = (l & 7) * 8;
            gload_lds16(A  + (size_t)(m0 + row) * K + kt * 64 + col, &As[rbase * 64]);
            gload_lds16(Bt + (size_t)(n0 + row) * K + kt * 64 + col, &Bs[rbase * 64]);
        }
        __syncthreads();
        #pragma unroll
        for (int ks = 0; ks < 2; ++ks) {
            bf16x8 af[4], bfv[4];
            #pragma unroll
            for (int i = 0; i < 4; ++i)
                af[i] = *(const bf16x8*)&As[(wr + i*16 + lr) * 64 + ks*32 + lh*8];
            #pragma unroll
            for (int j = 0; j < 4; ++j)
                bfv[j] = *(const bf16x8*)&Bs[(wc + j*16 + lr) * 64 + ks*32 + lh*8];
            #pragma unroll
            for (int i = 0; i < 4; ++i)
                #pragma unroll
                for (int j = 0; j < 4; ++j)
                    acc[i][j] = __builtin_amdgcn_mfma_f32_16x16x32_bf16(af[i], bfv[j], acc[i][j], 0, 0, 0);
        }
    }

    #pragma unroll
    for (int i = 0; i < 4; ++i) {
        #pragma unroll
        for (int j = 0; j < 4; ++j) {
            #pragma unroll
            for (int r = 0; r < 4; ++r) {
                int row = m0 + wr + i*16 + lh*4 + r;
                int col = n0 + wc + j*16 + lr;
                float v = acc[i][j][r] + bias[col];
                if (MODE == 0) {
                    int wh = col >> 10, h = (col >> 6) & 15, d = col & 63;
                    int b = row >> 11, s = row & 2047;
                    size_t base = (size_t)(b * NH + h);
                    unsigned short bv = f2bf(v);
                    if (wh == 0)      q [(base * SEQ + s) * HD + d] = bv;
                    else if (wh == 1) kk[(base * SEQ + s) * HD + d] = bv;
                    else              vt[(base * HD + d) * SEQ + s] = bv;
                } else if (MODE == 2) {
                    float g = 0.5f * v * (1.f + erff(v * 0.70710678118f));
                    outb[(size_t)row * N + col] = f2bf(g);
                } else {
                    outf[(size_t)row * N + col] = v + resid[(size_t)row * N + col];
                }
            }
        }
    }
}

// ---------------- flash attention: 1 block = (b,h, 64 q-rows), 4 waves x 16 rows ----------
__global__ __launch_bounds__(256)
void attn_kernel(const unsigned short* __restrict__ q,
                 const unsigned short* __restrict__ k,
                 const unsigned short* __restrict__ vt,
                 unsigned short* __restrict__ ctx)
{
    __shared__ __align__(16) unsigned short Qs[64 * 64];
    __shared__ __align__(16) unsigned short Ks[64 * 64];
    __shared__ __align__(16) unsigned short Vs[64 * 64];   // [d][s] within tile
    __shared__ __align__(16) unsigned short Ps[4][16 * 64];

    const int tid = threadIdx.x, w = tid >> 6, l = tid & 63;
    const int lr = l & 15, lh = l >> 4;
    const int qt = blockIdx.x, bh = blockIdx.y;
    const int b = bh >> 4, h = bh & 15;

    const unsigned short* qbase = q + ((size_t)bh * SEQ + qt * 64) * HD;
    #pragma unroll
    for (int c = 0; c < 2; ++c) {
        int ebase = (w * 2 + c) * 512;
        gload_lds16(qbase + ebase + l * 8, &Qs[ebase]);
    }
    __syncthreads();
    bf16x8 aq0 = *(const bf16x8*)&Qs[(w*16 + lr) * 64 +      lh*8];
    bf16x8 aq1 = *(const bf16x8*)&Qs[(w*16 + lr) * 64 + 32 + lh*8];

    float mrow[4], lrow[4];
    f32x4 o[4];
    #pragma unroll
    for (int r = 0; r < 4; ++r) { mrow[r] = -1e30f; lrow[r] = 0.f; }
    #pragma unroll
    for (int nf = 0; nf < 4; ++nf) o[nf] = {0.f, 0.f, 0.f, 0.f};

    for (int t = 0; t < SEQ / 64; ++t) {
        __syncthreads();
        const unsigned short* kbase = k + ((size_t)bh * SEQ + t * 64) * HD;
        #pragma unroll
        for (int c = 0; c < 2; ++c) {
            int ebase = (w * 2 + c) * 512;
            gload_lds16(kbase + ebase + l * 8, &Ks[ebase]);
        }
        const unsigned short* vbase = vt + (size_t)bh * HD * SEQ + t * 64;
        #pragma unroll
        for (int c = 0; c < 2; ++c) {
            int dd0 = w * 16 + c * 8;
            int dd = dd0 + (l >> 3), ssb = (l & 7) * 8;
            gload_lds16(vbase + (size_t)dd * SEQ + ssb, &Vs[dd0 * 64]);
        }
        __syncthreads();

        // scores = Q K^T / 8
        f32x4 sc[4];
        #pragma unroll
        for (int j = 0; j < 4; ++j) {
            bf16x8 kb0 = *(const bf16x8*)&Ks[(j*16 + lr) * 64 +      lh*8];
            bf16x8 kb1 = *(const bf16x8*)&Ks[(j*16 + lr) * 64 + 32 + lh*8];
            f32x4 z = {0.f, 0.f, 0.f, 0.f};
            z = __builtin_amdgcn_mfma_f32_16x16x32_bf16(aq0, kb0, z, 0, 0, 0);
            z = __builtin_amdgcn_mfma_f32_16x16x32_bf16(aq1, kb1, z, 0, 0, 0);
            sc[j] = z;
        }
        #pragma unroll
        for (int j = 0; j < 4; ++j)
            #pragma unroll
            for (int r = 0; r < 4; ++r) sc[j][r] *= 0.125f;

        float mnew[4], al[4], rs[4];
        #pragma unroll
        for (int r = 0; r < 4; ++r) {
            float mt = fmaxf(fmaxf(sc[0][r], sc[1][r]), fmaxf(sc[2][r], sc[3][r]));
            #pragma unroll
            for (int msk = 1; msk < 16; msk <<= 1) mt = fmaxf(mt, __shfl_xor(mt, msk));
            mnew[r] = fmaxf(mrow[r], mt);
            al[r] = expf(mrow[r] - mnew[r]);
            mrow[r] = mnew[r];
            rs[r] = 0.f;
        }
        float p[4][4];
        #pragma unroll
        for (int j = 0; j < 4; ++j)
            #pragma unroll
            for (int r = 0; r < 4; ++r) {
                p[j][r] = expf(sc[j][r] - mnew[r]);
                rs[r] += p[j][r];
            }
        #pragma unroll
        for (int r = 0; r < 4; ++r) {
            #pragma unroll
            for (int msk = 1; msk < 16; msk <<= 1) rs[r] += __shfl_xor(rs[r], msk);
            lrow[r] = lrow[r] * al[r] + rs[r];
        }
        #pragma unroll
        for (int nf = 0; nf < 4; ++nf)
            #pragma unroll
            for (int r = 0; r < 4; ++r) o[nf][r] *= al[r];

        // P (16x64, bf16) via LDS to re-layout for A-operand
        #pragma unroll
        for (int j = 0; j < 4; ++j)
            #pragma unroll
            for (int r = 0; r < 4; ++r)
                Ps[w][(lh*4 + r) * 64 + j*16 + lr] = f2bf(p[j][r]);

        bf16x8 ap0 = *(const bf16x8*)&Ps[w][lr * 64 +      lh*8];
        bf16x8 ap1 = *(const bf16x8*)&Ps[w][lr * 64 + 32 + lh*8];
        #pragma unroll
        for (int nf = 0; nf < 4; ++nf) {
            bf16x8 vb0 = *(const bf16x8*)&Vs[(nf*16 + lr) * 64 +      lh*8];
            bf16x8 vb1 = *(const bf16x8*)&Vs[(nf*16 + lr) * 64 + 32 + lh*8];
            o[nf] = __builtin_amdgcn_mfma_f32_16x16x32_bf16(ap0, vb0, o[nf], 0, 0, 0);
            o[nf] = __builtin_amdgcn_mfma_f32_16x16x32_bf16(ap1, vb1, o[nf], 0, 0, 0);
        }
    }

    #pragma unroll
    for (int nf = 0; nf < 4; ++nf)
        #pragma unroll
        for (int r = 0; r < 4; ++r) {
            int row = qt * 64 + w * 16 + lh * 4 + r;     // seq pos
            float val = o[nf][r] / lrow[r];
            ctx[((size_t)b * SEQ + row) * DM + h * 64 + nf * 16 + lr] = f2bf(val);
        }
}

extern "C" void kernel_launch(void* const* d_in, const int* in_sizes, int n_in,
                              void* d_out, int out_size, void* d_ws, size_t ws_size,
                              hipStream_t stream)
{
    const float* src   = (const float*)d_in[0];
    const float* qkv_w = (const float*)d_in[1];
    const float* qkv_b = (const float*)d_in[2];
    const float* out_w = (const float*)d_in[3];
    const float* out_b = (const float*)d_in[4];
    const float* ff1_w = (const float*)d_in[5];
    const float* ff1_b = (const float*)d_in[6];
    const float* ff2_w = (const float*)d_in[7];
    const float* ff2_b = (const float*)d_in[8];
    const float* n1_w  = (const float*)d_in[9];
    const float* n2_w  = (const float*)d_in[10];

    char* ws = (char*)d_ws;
    const size_t MB = 1u << 20;
    unsigned short* qkv_wt = (unsigned short*)(ws);            // 6 MB  [3072][1024]
    unsigned short* out_wt = (unsigned short*)(ws + 6*MB);     // 2 MB  [1024][1024]
    unsigned short* ff1_wt = (unsigned short*)(ws + 8*MB);     // 8 MB  [4096][1024]
    unsigned short* ff2_wt = (unsigned short*)(ws + 16*MB);    // 8 MB  [1024][4096]
    unsigned short* xb     = (unsigned short*)(ws + 24*MB);    // 16 MB
    unsigned short* qb     = (unsigned short*)(ws + 40*MB);    // 16 MB
    unsigned short* kb     = (unsigned short*)(ws + 56*MB);    // 16 MB
    unsigned short* vtb    = (unsigned short*)(ws + 72*MB);    // 16 MB
    unsigned short* hb     = (unsigned short*)(ws + 24*MB);    // 64 MB (overlays xb..vtb)
    unsigned short* ctxb   = (unsigned short*)(ws + 88*MB);    // 16 MB
    unsigned short* yb     = (unsigned short*)(ws + 88*MB);    // reuses ctx
    float*          src2   = (float*)(ws + 104*MB);            // 32 MB   (total 136 MB)
    float* outp = (float*)d_out;

    convT_kernel<<<dim3(3072/32, 1024/32), 256, 0, stream>>>(qkv_w, qkv_wt, 1024, 3072);
    convT_kernel<<<dim3(1024/32, 1024/32), 256, 0, stream>>>(out_w, out_wt, 1024, 1024);
    convT_kernel<<<dim3(4096/32, 1024/32), 256, 0, stream>>>(ff1_w, ff1_wt, 1024, 4096);
    convT_kernel<<<dim3(1024/32, 4096/32), 256, 0, stream>>>(ff2_w, ff2_wt, 4096, 1024);

    rmsnorm_kernel<<<NTOK, 256, 0, stream>>>(src, n1_w, xb);

    gemm_bf16<0><<<dim3(3072/128, NTOK/128), 256, 0, stream>>>(
        xb, qkv_wt, qkv_b, NTOK, 3072, 1024, nullptr, nullptr, nullptr, qb, kb, vtb);

    attn_kernel<<<dim3(SEQ/64, BATCH*NH), 256, 0, stream>>>(qb, kb, vtb, ctxb);

    gemm_bf16<1><<<dim3(1024/128, NTOK/128), 256, 0, stream>>>(
        ctxb, out_wt, out_b, NTOK, 1024, 1024, src, src2, nullptr, nullptr, nullptr, nullptr);

    rmsnorm_kernel<<<NTOK, 256, 0, stream>>>(src2, n2_w, yb);

    gemm_bf16<2><<<dim3(4096/128, NTOK/128), 256, 0, stream>>>(
        yb, ff1_wt, ff1_b, NTOK, 4096, 1024, nullptr, nullptr, hb, nullptr, nullptr, nullptr);

    gemm_bf16<3><<<dim3(1024/128, NTOK/128), 256, 0, stream>>>(
        hb, ff2_wt, ff2_b, NTOK, 1024, 4096, src2, outp, nullptr, nullptr, nullptr, nullptr);
}

// Round 2
// 610.202 us; speedup vs baseline: 1.1602x; 1.1602x over previous
//
#include <hip/hip_runtime.h>
#include <hip/hip_bf16.h>

#define DM   1024
#define DFF  4096
#define NH   16
#define HD   64
#define SEQ  2048
#define BATCH 4
#define NTOK (BATCH*SEQ)

typedef float  f32x4  __attribute__((ext_vector_type(4)));
typedef short  bf16x8 __attribute__((ext_vector_type(8)));

__device__ __forceinline__ unsigned short f2bf(float f) {
    unsigned int x = __builtin_bit_cast(unsigned int, f);
    x += 0x7fff + ((x >> 16) & 1);          // RNE; inputs finite
    return (unsigned short)(x >> 16);
}

__device__ __forceinline__ void gload_lds16(const void* g, void* l) {
    // dest is wave-uniform base; HW writes base + lane*16
    __builtin_amdgcn_global_load_lds(
        (const __attribute__((address_space(1))) unsigned int*)g,
        (__attribute__((address_space(3))) unsigned int*)l,
        16, 0, 0);
}

// XOR swizzle for [R][64] bf16 tiles: element index within row
__device__ __forceinline__ int swz(int row, int elem) { return elem ^ ((row & 7) << 3); }

// ---------------- weight fp32 -> bf16 transpose:  W[K][N] -> Wt[N][K] ----------------
__global__ __launch_bounds__(256)
void convT_kernel(const float* __restrict__ W, unsigned short* __restrict__ Wt, int K, int N)
{
    __shared__ float tile[32][33];
    int n0 = blockIdx.x * 32, k0 = blockIdx.y * 32;
    int tx = threadIdx.x & 31, ty = threadIdx.x >> 5;   // 32 x 8
    #pragma unroll
    for (int i = 0; i < 4; ++i)
        tile[ty + i*8][tx] = W[(size_t)(k0 + ty + i*8) * N + n0 + tx];
    __syncthreads();
    #pragma unroll
    for (int i = 0; i < 4; ++i)
        Wt[(size_t)(n0 + ty + i*8) * K + k0 + tx] = f2bf(tile[tx][ty + i*8]);
}

// ---------------- RMSNorm: fp32 in -> bf16 out ----------------
__global__ __launch_bounds__(256)
void rmsnorm_kernel(const float* __restrict__ in, const float* __restrict__ w,
                    unsigned short* __restrict__ out)
{
    __shared__ float red[4];
    int row = blockIdx.x, t = threadIdx.x;
    float4 v = ((const float4*)(in + (size_t)row * DM))[t];
    float ss = v.x*v.x + v.y*v.y + v.z*v.z + v.w*v.w;
    #pragma unroll
    for (int m = 1; m < 64; m <<= 1) ss += __shfl_xor(ss, m);
    if ((t & 63) == 0) red[t >> 6] = ss;
    __syncthreads();
    float tot = red[0] + red[1] + red[2] + red[3];
    float rms = sqrtf(tot) * (1.f / 32.f);      // ||x|| / sqrt(1024)
    float inv = 1.f / (rms + 1e-8f);
    float4 wv = ((const float4*)w)[t];
    unsigned int lo = (unsigned int)f2bf(v.x*inv*wv.x) | ((unsigned int)f2bf(v.y*inv*wv.y) << 16);
    unsigned int hi = (unsigned int)f2bf(v.z*inv*wv.z) | ((unsigned int)f2bf(v.w*inv*wv.w) << 16);
    uint2 pk; pk.x = lo; pk.y = hi;
    *(uint2*)(out + (size_t)row * DM + t * 4) = pk;
}

// ---------------- GEMM: C = A(bf16 [M][K]) @ Bt^T(bf16 [N][K]) + bias, fused epilogues ----
// MODE 0: qkv scatter -> q (prescaled 1/8), k (bf16 [B*H][S][64]), v transposed
// MODE 1: out = acc + bias + resid  (fp32)
// MODE 2: out = gelu(acc + bias)    (bf16)
// MODE 3: same as 1 (ff2 + residual -> d_out fp32)
template<int MODE>
__global__ __launch_bounds__(256)
void gemm_bf16(const unsigned short* __restrict__ A,
               const unsigned short* __restrict__ Bt,
               const float* __restrict__ bias,
               int M, int N, int K,
               const float* __restrict__ resid,
               float* __restrict__ outf,
               unsigned short* __restrict__ outb,
               unsigned short* __restrict__ q,
               unsigned short* __restrict__ kk,
               unsigned short* __restrict__ vt)
{
    __shared__ __align__(16) unsigned short As[128 * 64];
    __shared__ __align__(16) unsigned short Bs[128 * 64];
    const int tid = threadIdx.x;
    const int w = tid >> 6, l = tid & 63;
    const int lr = l & 15, lh = l >> 4;
    const int m0 = blockIdx.y * 128, n0 = blockIdx.x * 128;
    const int wr = (w >> 1) * 64, wc = (w & 1) * 64;

    f32x4 acc[4][4];
    #pragma unroll
    for (int i = 0; i < 4; ++i)
        #pragma unroll
        for (int j = 0; j < 4; ++j) acc[i][j] = {0.f, 0.f, 0.f, 0.f};

    const int nkt = K >> 6;
    for (int kt = 0; kt < nkt; ++kt) {
        __syncthreads();
        #pragma unroll
        for (int c = 0; c < 4; ++c) {
            int rbase = w * 32 + c * 8;
            int row = rbase + (l >> 3);
            int col = (l & 7) * 8;
            gload_lds16(A  + (size_t)(m0 + row) * K + kt * 64 + col, &As[rbase * 64]);
            gload_lds16(Bt + (size_t)(n0 + row) * K + kt * 64 + col, &Bs[rbase * 64]);
        }
        __syncthreads();
        #pragma unroll
        for (int ks = 0; ks < 2; ++ks) {
            bf16x8 af[4], bfv[4];
            #pragma unroll
            for (int i = 0; i < 4; ++i)
                af[i] = *(const bf16x8*)&As[(wr + i*16 + lr) * 64 + ks*32 + lh*8];
            #pragma unroll
            for (int j = 0; j < 4; ++j)
                bfv[j] = *(const bf16x8*)&Bs[(wc + j*16 + lr) * 64 + ks*32 + lh*8];
            #pragma unroll
            for (int i = 0; i < 4; ++i)
                #pragma unroll
                for (int j = 0; j < 4; ++j)
                    acc[i][j] = __builtin_amdgcn_mfma_f32_16x16x32_bf16(af[i], bfv[j], acc[i][j], 0, 0, 0);
        }
    }

    #pragma unroll
    for (int i = 0; i < 4; ++i) {
        #pragma unroll
        for (int j = 0; j < 4; ++j) {
            #pragma unroll
            for (int r = 0; r < 4; ++r) {
                int row = m0 + wr + i*16 + lh*4 + r;
                int col = n0 + wc + j*16 + lr;
                float v = acc[i][j][r] + bias[col];
                if (MODE == 0) {
                    int wh = col >> 10, h = (col >> 6) & 15, d = col & 63;
                    int b = row >> 11, s = row & 2047;
                    size_t base = (size_t)(b * NH + h);
                    if (wh == 0)      q [(base * SEQ + s) * HD + d] = f2bf(v * 0.125f);
                    else if (wh == 1) kk[(base * SEQ + s) * HD + d] = f2bf(v);
                    else              vt[(base * HD + d) * SEQ + s] = f2bf(v);
                } else if (MODE == 2) {
                    float g = 0.5f * v * (1.f + erff(v * 0.70710678118f));
                    outb[(size_t)row * N + col] = f2bf(g);
                } else {
                    outf[(size_t)row * N + col] = v + resid[(size_t)row * N + col];
                }
            }
        }
    }
}

// ---------------- flash attention: 1 block = (b,h, 64 q-rows), 4 waves x 16 rows ----------
// LDS tiles XOR-swizzled (T2); staging pre-swizzles the global source (rule 21).
__global__ __launch_bounds__(256)
void attn_kernel(const unsigned short* __restrict__ q,
                 const unsigned short* __restrict__ k,
                 const unsigned short* __restrict__ vt,
                 unsigned short* __restrict__ ctx)
{
    __shared__ __align__(16) unsigned short Qs[64 * 64];
    __shared__ __align__(16) unsigned short Ks[64 * 64];
    __shared__ __align__(16) unsigned short Vs[64 * 64];   // [d][s] within tile
    __shared__ __align__(16) unsigned short Ps[4][16 * 64];

    const int tid = threadIdx.x, w = tid >> 6, l = tid & 63;
    const int lr = l & 15, lh = l >> 4;

    // XCD-chunked swizzle: 2048 blocks = 8 XCDs x 256; each XCD owns 8 heads
    const int sid = (blockIdx.x & 7) * 256 + (blockIdx.x >> 3);
    const int bh = sid >> 5, qt = sid & 31;
    const int b = bh >> 4, h = bh & 15;

    // per-lane staging geometry for one 8-row x 64-col chunk (1024 lanes*16B)
    const int rloc = l >> 3;                         // row within chunk
    const int cswz = (((l & 7) ^ rloc) << 3);        // pre-swizzled source col (elems)

    const unsigned short* qbase = q + ((size_t)bh * SEQ + qt * 64) * HD;
    #pragma unroll
    for (int c = 0; c < 2; ++c) {
        int r0 = (w * 2 + c) * 8;                    // chunk row base (mult of 8)
        gload_lds16(qbase + (size_t)(r0 + rloc) * HD + cswz, &Qs[r0 * 64]);
    }
    __syncthreads();
    const int qrow = w * 16 + lr;
    bf16x8 aq0 = *(const bf16x8*)&Qs[qrow * 64 + swz(qrow,      lh * 8)];
    bf16x8 aq1 = *(const bf16x8*)&Qs[qrow * 64 + swz(qrow, 32 + lh * 8)];

    float mrow[4], lrow[4];
    f32x4 o[4];
    #pragma unroll
    for (int r = 0; r < 4; ++r) { mrow[r] = -1e30f; lrow[r] = 0.f; }
    #pragma unroll
    for (int nf = 0; nf < 4; ++nf) o[nf] = {0.f, 0.f, 0.f, 0.f};

    for (int t = 0; t < SEQ / 64; ++t) {
        __syncthreads();
        const unsigned short* kbase = k + ((size_t)bh * SEQ + t * 64) * HD;
        #pragma unroll
        for (int c = 0; c < 2; ++c) {
            int r0 = (w * 2 + c) * 8;
            gload_lds16(kbase + (size_t)(r0 + rloc) * HD + cswz, &Ks[r0 * 64]);
        }
        const unsigned short* vbase = vt + (size_t)bh * HD * SEQ + t * 64;
        #pragma unroll
        for (int c = 0; c < 2; ++c) {
            int d0 = w * 16 + c * 8;                 // chunk row base in d
            gload_lds16(vbase + (size_t)(d0 + rloc) * SEQ + cswz, &Vs[d0 * 64]);
        }
        __syncthreads();

        // scores = (Q/8) K^T   (Q prescaled at QKV epilogue)
        f32x4 sc[4];
        #pragma unroll
        for (int j = 0; j < 4; ++j) {
            int kr = j * 16 + lr;
            bf16x8 kb0 = *(const bf16x8*)&Ks[kr * 64 + swz(kr,      lh * 8)];
            bf16x8 kb1 = *(const bf16x8*)&Ks[kr * 64 + swz(kr, 32 + lh * 8)];
            f32x4 z = {0.f, 0.f, 0.f, 0.f};
            z = __builtin_amdgcn_mfma_f32_16x16x32_bf16(aq0, kb0, z, 0, 0, 0);
            z = __builtin_amdgcn_mfma_f32_16x16x32_bf16(aq1, kb1, z, 0, 0, 0);
            sc[j] = z;
        }

        float mnew[4], al[4], rs[4];
        #pragma unroll
        for (int r = 0; r < 4; ++r) {
            float mt = fmaxf(fmaxf(sc[0][r], sc[1][r]), fmaxf(sc[2][r], sc[3][r]));
            #pragma unroll
            for (int msk = 1; msk < 16; msk <<= 1) mt = fmaxf(mt, __shfl_xor(mt, msk));
            mnew[r] = fmaxf(mrow[r], mt);
            al[r] = __expf(mrow[r] - mnew[r]);
            mrow[r] = mnew[r];
            rs[r] = 0.f;
        }
        float p[4][4];
        #pragma unroll
        for (int j = 0; j < 4; ++j)
            #pragma unroll
            for (int r = 0; r < 4; ++r) {
                p[j][r] = __expf(sc[j][r] - mnew[r]);
                rs[r] += p[j][r];
            }
        #pragma unroll
        for (int r = 0; r < 4; ++r) {
            #pragma unroll
            for (int msk = 1; msk < 16; msk <<= 1) rs[r] += __shfl_xor(rs[r], msk);
            lrow[r] = lrow[r] * al[r] + rs[r];
        }
        #pragma unroll
        for (int nf = 0; nf < 4; ++nf)
            #pragma unroll
            for (int r = 0; r < 4; ++r) o[nf][r] *= al[r];

        // P (16x64, bf16) via LDS (swizzled) to re-layout for A-operand
        #pragma unroll
        for (int j = 0; j < 4; ++j)
            #pragma unroll
            for (int r = 0; r < 4; ++r) {
                int pr = lh * 4 + r, pc = j * 16 + lr;
                Ps[w][pr * 64 + swz(pr, pc)] = f2bf(p[j][r]);
            }

        bf16x8 ap0 = *(const bf16x8*)&Ps[w][lr * 64 + swz(lr,      lh * 8)];
        bf16x8 ap1 = *(const bf16x8*)&Ps[w][lr * 64 + swz(lr, 32 + lh * 8)];
        #pragma unroll
        for (int nf = 0; nf < 4; ++nf) {
            int vr = nf * 16 + lr;
            bf16x8 vb0 = *(const bf16x8*)&Vs[vr * 64 + swz(vr,      lh * 8)];
            bf16x8 vb1 = *(const bf16x8*)&Vs[vr * 64 + swz(vr, 32 + lh * 8)];
            o[nf] = __builtin_amdgcn_mfma_f32_16x16x32_bf16(ap0, vb0, o[nf], 0, 0, 0);
            o[nf] = __builtin_amdgcn_mfma_f32_16x16x32_bf16(ap1, vb1, o[nf], 0, 0, 0);
        }
    }

    #pragma unroll
    for (int nf = 0; nf < 4; ++nf)
        #pragma unroll
        for (int r = 0; r < 4; ++r) {
            int row = qt * 64 + w * 16 + lh * 4 + r;     // seq pos
            float val = o[nf][r] / lrow[r];
            ctx[((size_t)b * SEQ + row) * DM + h * 64 + nf * 16 + lr] = f2bf(val);
        }
}

extern "C" void kernel_launch(void* const* d_in, const int* in_sizes, int n_in,
                              void* d_out, int out_size, void* d_ws, size_t ws_size,
                              hipStream_t stream)
{
    const float* src   = (const float*)d_in[0];
    const float* qkv_w = (const float*)d_in[1];
    const float* qkv_b = (const float*)d_in[2];
    const float* out_w = (const float*)d_in[3];
    const float* out_b = (const float*)d_in[4];
    const float* ff1_w = (const float*)d_in[5];
    const float* ff1_b = (const float*)d_in[6];
    const float* ff2_w = (const float*)d_in[7];
    const float* ff2_b = (const float*)d_in[8];
    const float* n1_w  = (const float*)d_in[9];
    const float* n2_w  = (const float*)d_in[10];

    char* ws = (char*)d_ws;
    const size_t MB = 1u << 20;
    unsigned short* qkv_wt = (unsigned short*)(ws);            // 6 MB  [3072][1024]
    unsigned short* out_wt = (unsigned short*)(ws + 6*MB);     // 2 MB  [1024][1024]
    unsigned short* ff1_wt = (unsigned short*)(ws + 8*MB);     // 8 MB  [4096][1024]
    unsigned short* ff2_wt = (unsigned short*)(ws + 16*MB);    // 8 MB  [1024][4096]
    unsigned short* xb     = (unsigned short*)(ws + 24*MB);    // 16 MB
    unsigned short* qb     = (unsigned short*)(ws + 40*MB);    // 16 MB
    unsigned short* kb     = (unsigned short*)(ws + 56*MB);    // 16 MB
    unsigned short* vtb    = (unsigned short*)(ws + 72*MB);    // 16 MB
    unsigned short* hb     = (unsigned short*)(ws + 24*MB);    // 64 MB (overlays xb..vtb)
    unsigned short* ctxb   = (unsigned short*)(ws + 88*MB);    // 16 MB
    unsigned short* yb     = (unsigned short*)(ws + 88*MB);    // reuses ctx
    float*          src2   = (float*)(ws + 104*MB);            // 32 MB   (total 136 MB)
    float* outp = (float*)d_out;

    convT_kernel<<<dim3(3072/32, 1024/32), 256, 0, stream>>>(qkv_w, qkv_wt, 1024, 3072);
    convT_kernel<<<dim3(1024/32, 1024/32), 256, 0, stream>>>(out_w, out_wt, 1024, 1024);
    convT_kernel<<<dim3(4096/32, 1024/32), 256, 0, stream>>>(ff1_w, ff1_wt, 1024, 4096);
    convT_kernel<<<dim3(1024/32, 4096/32), 256, 0, stream>>>(ff2_w, ff2_wt, 4096, 1024);

    rmsnorm_kernel<<<NTOK, 256, 0, stream>>>(src, n1_w, xb);

    gemm_bf16<0><<<dim3(3072/128, NTOK/128), 256, 0, stream>>>(
        xb, qkv_wt, qkv_b, NTOK, 3072, 1024, nullptr, nullptr, nullptr, qb, kb, vtb);

    attn_kernel<<<SEQ/64 * BATCH*NH, 256, 0, stream>>>(qb, kb, vtb, ctxb);

    gemm_bf16<1><<<dim3(1024/128, NTOK/128), 256, 0, stream>>>(
        ctxb, out_wt, out_b, NTOK, 1024, 1024, src, src2, nullptr, nullptr, nullptr, nullptr);

    rmsnorm_kernel<<<NTOK, 256, 0, stream>>>(src2, n2_w, yb);

    gemm_bf16<2><<<dim3(4096/128, NTOK/128), 256, 0, stream>>>(
        yb, ff1_wt, ff1_b, NTOK, 4096, 1024, nullptr, nullptr, hb, nullptr, nullptr, nullptr);

    gemm_bf16<3><<<dim3(1024/128, NTOK/128), 256, 0, stream>>>(
        hb, ff2_wt, ff2_b, NTOK, 1024, 4096, src2, outp, nullptr, nullptr, nullptr, nullptr);
}

// Round 3
// 538.592 us; speedup vs baseline: 1.3144x; 1.1330x over previous
//
#include <hip/hip_runtime.h>
#include <hip/hip_bf16.h>

#define DM   1024
#define DFF  4096
#define NH   16
#define HD   64
#define SEQ  2048
#define BATCH 4
#define NTOK (BATCH*SEQ)

typedef float  f32x4  __attribute__((ext_vector_type(4)));
typedef short  bf16x8 __attribute__((ext_vector_type(8)));

__device__ __forceinline__ unsigned short f2bf(float f) {
    unsigned int x = __builtin_bit_cast(unsigned int, f);
    x += 0x7fff + ((x >> 16) & 1);          // RNE; inputs finite
    return (unsigned short)(x >> 16);
}

__device__ __forceinline__ void gload_lds16(const void* g, void* l) {
    // dest is wave-uniform base; HW writes base + lane*16
    __builtin_amdgcn_global_load_lds(
        (const __attribute__((address_space(1))) unsigned int*)g,
        (__attribute__((address_space(3))) unsigned int*)l,
        16, 0, 0);
}

// XOR swizzle for [R][64] bf16 tiles: element index within row
__device__ __forceinline__ int swz(int row, int elem) { return elem ^ ((row & 7) << 3); }

// ---------------- weight fp32 -> bf16 transpose:  W[K][N] -> Wt[N][K] ----------------
__global__ __launch_bounds__(256)
void convT_kernel(const float* __restrict__ W, unsigned short* __restrict__ Wt, int K, int N)
{
    __shared__ float tile[32][33];
    int n0 = blockIdx.x * 32, k0 = blockIdx.y * 32;
    int tx = threadIdx.x & 31, ty = threadIdx.x >> 5;   // 32 x 8
    #pragma unroll
    for (int i = 0; i < 4; ++i)
        tile[ty + i*8][tx] = W[(size_t)(k0 + ty + i*8) * N + n0 + tx];
    __syncthreads();
    #pragma unroll
    for (int i = 0; i < 4; ++i)
        Wt[(size_t)(n0 + ty + i*8) * K + k0 + tx] = f2bf(tile[tx][ty + i*8]);
}

// ---------------- RMSNorm: fp32 in -> bf16 out ----------------
__global__ __launch_bounds__(256)
void rmsnorm_kernel(const float* __restrict__ in, const float* __restrict__ w,
                    unsigned short* __restrict__ out)
{
    __shared__ float red[4];
    int row = blockIdx.x, t = threadIdx.x;
    float4 v = ((const float4*)(in + (size_t)row * DM))[t];
    float ss = v.x*v.x + v.y*v.y + v.z*v.z + v.w*v.w;
    #pragma unroll
    for (int m = 1; m < 64; m <<= 1) ss += __shfl_xor(ss, m);
    if ((t & 63) == 0) red[t >> 6] = ss;
    __syncthreads();
    float tot = red[0] + red[1] + red[2] + red[3];
    float rms = sqrtf(tot) * (1.f / 32.f);      // ||x|| / sqrt(1024)
    float inv = 1.f / (rms + 1e-8f);
    float4 wv = ((const float4*)w)[t];
    unsigned int lo = (unsigned int)f2bf(v.x*inv*wv.x) | ((unsigned int)f2bf(v.y*inv*wv.y) << 16);
    unsigned int hi = (unsigned int)f2bf(v.z*inv*wv.z) | ((unsigned int)f2bf(v.w*inv*wv.w) << 16);
    uint2 pk; pk.x = lo; pk.y = hi;
    *(uint2*)(out + (size_t)row * DM + t * 4) = pk;
}

// ---------------- GEMM: C = A(bf16 [M][K]) @ Bt^T(bf16 [N][K]) + bias, fused epilogues ----
// MODE 0: qkv scatter -> q (prescaled 1/8), k (bf16 [B*H][S][64]), v transposed
// MODE 1: out = acc + bias + resid  (fp32)
// MODE 2: out = gelu(acc + bias)    (bf16)
// MODE 3: same as 1 (ff2 + residual -> d_out fp32)
template<int MODE>
__global__ __launch_bounds__(256)
void gemm_bf16(const unsigned short* __restrict__ A,
               const unsigned short* __restrict__ Bt,
               const float* __restrict__ bias,
               int M, int N, int K,
               const float* __restrict__ resid,
               float* __restrict__ outf,
               unsigned short* __restrict__ outb,
               unsigned short* __restrict__ q,
               unsigned short* __restrict__ kk,
               unsigned short* __restrict__ vt)
{
    __shared__ __align__(16) unsigned short As[128 * 64];
    __shared__ __align__(16) unsigned short Bs[128 * 64];
    const int tid = threadIdx.x;
    const int w = tid >> 6, l = tid & 63;
    const int lr = l & 15, lh = l >> 4;
    const int m0 = blockIdx.y * 128, n0 = blockIdx.x * 128;
    const int wr = (w >> 1) * 64, wc = (w & 1) * 64;

    f32x4 acc[4][4];
    #pragma unroll
    for (int i = 0; i < 4; ++i)
        #pragma unroll
        for (int j = 0; j < 4; ++j) acc[i][j] = {0.f, 0.f, 0.f, 0.f};

    const int nkt = K >> 6;
    for (int kt = 0; kt < nkt; ++kt) {
        __syncthreads();
        #pragma unroll
        for (int c = 0; c < 4; ++c) {
            int rbase = w * 32 + c * 8;
            int row = rbase + (l >> 3);
            int col = (l & 7) * 8;
            gload_lds16(A  + (size_t)(m0 + row) * K + kt * 64 + col, &As[rbase * 64]);
            gload_lds16(Bt + (size_t)(n0 + row) * K + kt * 64 + col, &Bs[rbase * 64]);
        }
        __syncthreads();
        #pragma unroll
        for (int ks = 0; ks < 2; ++ks) {
            bf16x8 af[4], bfv[4];
            #pragma unroll
            for (int i = 0; i < 4; ++i)
                af[i] = *(const bf16x8*)&As[(wr + i*16 + lr) * 64 + ks*32 + lh*8];
            #pragma unroll
            for (int j = 0; j < 4; ++j)
                bfv[j] = *(const bf16x8*)&Bs[(wc + j*16 + lr) * 64 + ks*32 + lh*8];
            #pragma unroll
            for (int i = 0; i < 4; ++i)
                #pragma unroll
                for (int j = 0; j < 4; ++j)
                    acc[i][j] = __builtin_amdgcn_mfma_f32_16x16x32_bf16(af[i], bfv[j], acc[i][j], 0, 0, 0);
        }
    }

    #pragma unroll
    for (int i = 0; i < 4; ++i) {
        #pragma unroll
        for (int j = 0; j < 4; ++j) {
            #pragma unroll
            for (int r = 0; r < 4; ++r) {
                int row = m0 + wr + i*16 + lh*4 + r;
                int col = n0 + wc + j*16 + lr;
                float v = acc[i][j][r] + bias[col];
                if (MODE == 0) {
                    int wh = col >> 10, h = (col >> 6) & 15, d = col & 63;
                    int b = row >> 11, s = row & 2047;
                    size_t base = (size_t)(b * NH + h);
                    if (wh == 0)      q [(base * SEQ + s) * HD + d] = f2bf(v * 0.125f);
                    else if (wh == 1) kk[(base * SEQ + s) * HD + d] = f2bf(v);
                    else              vt[(base * HD + d) * SEQ + s] = f2bf(v);
                } else if (MODE == 2) {
                    float g = 0.5f * v * (1.f + erff(v * 0.70710678118f));
                    outb[(size_t)row * N + col] = f2bf(g);
                } else {
                    outf[(size_t)row * N + col] = v + resid[(size_t)row * N + col];
                }
            }
        }
    }
}

// ---------------- flash attention: 1 block = (b,h, 64 q-rows), 4 waves x 16 rows ----------
// Swapped QK^T (lane owns one q-row's scores) + in-lane softmax + cvt_pk P pack.
// K/V double-buffered; one barrier per tile. LDS tiles XOR-swizzled (T2).
__global__ __launch_bounds__(256)
void attn_kernel(const unsigned short* __restrict__ q,
                 const unsigned short* __restrict__ k,
                 const unsigned short* __restrict__ vt,
                 unsigned short* __restrict__ ctx)
{
    __shared__ __align__(16) unsigned short Qs[64 * 64];
    __shared__ __align__(16) unsigned short Ks[2][64 * 64];
    __shared__ __align__(16) unsigned short Vs[2][64 * 64];   // [d][s] within tile
    __shared__ __align__(16) unsigned short Ps[4][16 * 64];

    const int tid = threadIdx.x, w = tid >> 6, l = tid & 63;
    const int lr = l & 15, lh = l >> 4;

    // XCD-chunked swizzle: 2048 blocks = 8 XCDs x 256; each XCD owns 8 heads
    const int sid = (blockIdx.x & 7) * 256 + (blockIdx.x >> 3);
    const int bh = sid >> 5, qt = sid & 31;
    const int b = bh >> 4, h = bh & 15;

    // per-lane staging geometry for one 8-row x 64-col chunk (1024 lanes*16B)
    const int rloc = l >> 3;                         // row within chunk
    const int cswz = (((l & 7) ^ rloc) << 3);        // pre-swizzled source col (elems)

    const unsigned short* kbase0 = k  + (size_t)bh * SEQ * HD;
    const unsigned short* vbase0 = vt + (size_t)bh * HD * SEQ;

    // prologue: stage Q + K/V tile 0 into buffer 0
    const unsigned short* qbase = q + ((size_t)bh * SEQ + qt * 64) * HD;
    #pragma unroll
    for (int c = 0; c < 2; ++c) {
        int r0 = (w * 2 + c) * 8;
        gload_lds16(qbase + (size_t)(r0 + rloc) * HD + cswz, &Qs[r0 * 64]);
        gload_lds16(kbase0 + (size_t)(r0 + rloc) * HD + cswz, &Ks[0][r0 * 64]);
    }
    #pragma unroll
    for (int c = 0; c < 2; ++c) {
        int d0 = w * 16 + c * 8;
        gload_lds16(vbase0 + (size_t)(d0 + rloc) * SEQ + cswz, &Vs[0][d0 * 64]);
    }
    __syncthreads();

    const int qrow = w * 16 + lr;
    bf16x8 aq0 = *(const bf16x8*)&Qs[qrow * 64 + swz(qrow,      lh * 8)];
    bf16x8 aq1 = *(const bf16x8*)&Qs[qrow * 64 + swz(qrow, 32 + lh * 8)];

    float mrow = -1e30f, lrow = 0.f;
    f32x4 o[4];
    #pragma unroll
    for (int nf = 0; nf < 4; ++nf) o[nf] = {0.f, 0.f, 0.f, 0.f};

    for (int t = 0; t < SEQ / 64; ++t) {
        const int cur = t & 1;
        // stage next tile into other buffer (loads in flight across compute)
        if (t + 1 < SEQ / 64) {
            const unsigned short* kb = kbase0 + (size_t)(t + 1) * 64 * HD;
            #pragma unroll
            for (int c = 0; c < 2; ++c) {
                int r0 = (w * 2 + c) * 8;
                gload_lds16(kb + (size_t)(r0 + rloc) * HD + cswz, &Ks[cur ^ 1][r0 * 64]);
            }
            const unsigned short* vb = vbase0 + (t + 1) * 64;
            #pragma unroll
            for (int c = 0; c < 2; ++c) {
                int d0 = w * 16 + c * 8;
                gload_lds16(vb + (size_t)(d0 + rloc) * SEQ + cswz, &Vs[cur ^ 1][d0 * 64]);
            }
        }

        const unsigned short* Kc = &Ks[cur][0];
        const unsigned short* Vc = &Vs[cur][0];

        // scores: swapped mfma(K, Q) -> lane holds S[q=lr][k = j*16 + lh*4 + r]
        f32x4 sc[4];
        __builtin_amdgcn_s_setprio(1);
        #pragma unroll
        for (int j = 0; j < 4; ++j) {
            int kr = j * 16 + lr;
            bf16x8 kb0 = *(const bf16x8*)&Kc[kr * 64 + swz(kr,      lh * 8)];
            bf16x8 kb1 = *(const bf16x8*)&Kc[kr * 64 + swz(kr, 32 + lh * 8)];
            f32x4 z = {0.f, 0.f, 0.f, 0.f};
            z = __builtin_amdgcn_mfma_f32_16x16x32_bf16(kb0, aq0, z, 0, 0, 0);
            z = __builtin_amdgcn_mfma_f32_16x16x32_bf16(kb1, aq1, z, 0, 0, 0);
            sc[j] = z;
        }
        __builtin_amdgcn_s_setprio(0);

        // in-lane row max (15 ops) + 2 shfl to cover all 64 k of the tile
        float mt = fmaxf(fmaxf(sc[0][0], sc[0][1]), fmaxf(sc[0][2], sc[0][3]));
        #pragma unroll
        for (int j = 1; j < 4; ++j)
            mt = fmaxf(mt, fmaxf(fmaxf(sc[j][0], sc[j][1]), fmaxf(sc[j][2], sc[j][3])));
        mt = fmaxf(mt, __shfl_xor(mt, 16));
        mt = fmaxf(mt, __shfl_xor(mt, 32));
        float mnew = fmaxf(mrow, mt);
        float al = __expf(mrow - mnew);
        mrow = mnew;

        float p[4][4];
        float rs = 0.f;
        #pragma unroll
        for (int j = 0; j < 4; ++j)
            #pragma unroll
            for (int r = 0; r < 4; ++r) {
                p[j][r] = __expf(sc[j][r] - mnew);
                rs += p[j][r];
            }
        rs += __shfl_xor(rs, 16);
        rs += __shfl_xor(rs, 32);
        lrow = lrow * al + rs;

        // broadcast rescale factor to O layout rows (lane's o rows are lh*4+r)
        float alo[4];
        #pragma unroll
        for (int r = 0; r < 4; ++r) alo[r] = __shfl(al, lh * 4 + r);
        #pragma unroll
        for (int nf = 0; nf < 4; ++nf)
            #pragma unroll
            for (int r = 0; r < 4; ++r) o[nf][r] *= alo[r];

        // pack P -> bf16 pairs, write to swizzled Ps[w] ([q=lr][k])
        unsigned short* Pw = &Ps[w][0];
        #pragma unroll
        for (int j = 0; j < 4; ++j) {
            int k0 = j * 16 + lh * 4;
            unsigned int w0, w1;
            asm("v_cvt_pk_bf16_f32 %0, %1, %2" : "=v"(w0) : "v"(p[j][0]), "v"(p[j][1]));
            asm("v_cvt_pk_bf16_f32 %0, %1, %2" : "=v"(w1) : "v"(p[j][2]), "v"(p[j][3]));
            int e = lr * 64 + (k0 ^ ((lr & 7) << 3));
            *(unsigned int*)&Pw[e]     = w0;
            *(unsigned int*)&Pw[e + 2] = w1;
        }
        bf16x8 ap0 = *(const bf16x8*)&Pw[lr * 64 + swz(lr,      lh * 8)];
        bf16x8 ap1 = *(const bf16x8*)&Pw[lr * 64 + swz(lr, 32 + lh * 8)];

        __builtin_amdgcn_s_setprio(1);
        #pragma unroll
        for (int nf = 0; nf < 4; ++nf) {
            int vr = nf * 16 + lr;
            bf16x8 vb0 = *(const bf16x8*)&Vc[vr * 64 + swz(vr,      lh * 8)];
            bf16x8 vb1 = *(const bf16x8*)&Vc[vr * 64 + swz(vr, 32 + lh * 8)];
            o[nf] = __builtin_amdgcn_mfma_f32_16x16x32_bf16(ap0, vb0, o[nf], 0, 0, 0);
            o[nf] = __builtin_amdgcn_mfma_f32_16x16x32_bf16(ap1, vb1, o[nf], 0, 0, 0);
        }
        __builtin_amdgcn_s_setprio(0);

        __syncthreads();   // drains next-tile staging; all waves done with cur buffers
    }

    float linv = 1.f / lrow;           // lane holds l for row q=lr
    float lo4[4];
    #pragma unroll
    for (int r = 0; r < 4; ++r) lo4[r] = __shfl(linv, lh * 4 + r);
    #pragma unroll
    for (int nf = 0; nf < 4; ++nf)
        #pragma unroll
        for (int r = 0; r < 4; ++r) {
            int row = qt * 64 + w * 16 + lh * 4 + r;     // seq pos
            ctx[((size_t)b * SEQ + row) * DM + h * 64 + nf * 16 + lr] = f2bf(o[nf][r] * lo4[r]);
        }
}

extern "C" void kernel_launch(void* const* d_in, const int* in_sizes, int n_in,
                              void* d_out, int out_size, void* d_ws, size_t ws_size,
                              hipStream_t stream)
{
    const float* src   = (const float*)d_in[0];
    const float* qkv_w = (const float*)d_in[1];
    const float* qkv_b = (const float*)d_in[2];
    const float* out_w = (const float*)d_in[3];
    const float* out_b = (const float*)d_in[4];
    const float* ff1_w = (const float*)d_in[5];
    const float* ff1_b = (const float*)d_in[6];
    const float* ff2_w = (const float*)d_in[7];
    const float* ff2_b = (const float*)d_in[8];
    const float* n1_w  = (const float*)d_in[9];
    const float* n2_w  = (const float*)d_in[10];

    char* ws = (char*)d_ws;
    const size_t MB = 1u << 20;
    unsigned short* qkv_wt = (unsigned short*)(ws);            // 6 MB  [3072][1024]
    unsigned short* out_wt = (unsigned short*)(ws + 6*MB);     // 2 MB  [1024][1024]
    unsigned short* ff1_wt = (unsigned short*)(ws + 8*MB);     // 8 MB  [4096][1024]
    unsigned short* ff2_wt = (unsigned short*)(ws + 16*MB);    // 8 MB  [1024][4096]
    unsigned short* xb     = (unsigned short*)(ws + 24*MB);    // 16 MB
    unsigned short* qb     = (unsigned short*)(ws + 40*MB);    // 16 MB
    unsigned short* kb     = (unsigned short*)(ws + 56*MB);    // 16 MB
    unsigned short* vtb    = (unsigned short*)(ws + 72*MB);    // 16 MB
    unsigned short* hb     = (unsigned short*)(ws + 24*MB);    // 64 MB (overlays xb..vtb)
    unsigned short* ctxb   = (unsigned short*)(ws + 88*MB);    // 16 MB
    unsigned short* yb     = (unsigned short*)(ws + 88*MB);    // reuses ctx
    float*          src2   = (float*)(ws + 104*MB);            // 32 MB   (total 136 MB)
    float* outp = (float*)d_out;

    convT_kernel<<<dim3(3072/32, 1024/32), 256, 0, stream>>>(qkv_w, qkv_wt, 1024, 3072);
    convT_kernel<<<dim3(1024/32, 1024/32), 256, 0, stream>>>(out_w, out_wt, 1024, 1024);
    convT_kernel<<<dim3(4096/32, 1024/32), 256, 0, stream>>>(ff1_w, ff1_wt, 1024, 4096);
    convT_kernel<<<dim3(1024/32, 4096/32), 256, 0, stream>>>(ff2_w, ff2_wt, 4096, 1024);

    rmsnorm_kernel<<<NTOK, 256, 0, stream>>>(src, n1_w, xb);

    gemm_bf16<0><<<dim3(3072/128, NTOK/128), 256, 0, stream>>>(
        xb, qkv_wt, qkv_b, NTOK, 3072, 1024, nullptr, nullptr, nullptr, qb, kb, vtb);

    attn_kernel<<<SEQ/64 * BATCH*NH, 256, 0, stream>>>(qb, kb, vtb, ctxb);

    gemm_bf16<1><<<dim3(1024/128, NTOK/128), 256, 0, stream>>>(
        ctxb, out_wt, out_b, NTOK, 1024, 1024, src, src2, nullptr, nullptr, nullptr, nullptr);

    rmsnorm_kernel<<<NTOK, 256, 0, stream>>>(src2, n2_w, yb);

    gemm_bf16<2><<<dim3(4096/128, NTOK/128), 256, 0, stream>>>(
        yb, ff1_wt, ff1_b, NTOK, 4096, 1024, nullptr, nullptr, hb, nullptr, nullptr, nullptr);

    gemm_bf16<3><<<dim3(1024/128, NTOK/128), 256, 0, stream>>>(
        hb, ff2_wt, ff2_b, NTOK, 1024, 4096, src2, outp, nullptr, nullptr, nullptr, nullptr);
}